// Round 6
// baseline (720.043 us; speedup 1.0000x reference)
//
#include <hip/hip_runtime.h>
#include <hip/hip_bf16.h>
#include <math.h>

#define NFEAT 512
#define SCAN_BS 256
#define PART_ITER 8           // edges per thread in partition/place (2048/block)
#define BUCK_SHIFT 10         // 1024 nodes per bucket -> ~256KB CSR window

// ============================================================================
// Phase A: h1p = x @ W1  ([N,512] @ [512,8]) — wave-per-node GEMV.
// Lane owns features [lane*8, lane*8+8); W1 fragment in 64 VGPRs preloaded
// once. Row read fully coalesced (64 lanes x 32B = 2KB). HBM floor: 205MB.
// ============================================================================
__global__ __launch_bounds__(256) void gcn_mm512x8(
    const float* __restrict__ x, const float* __restrict__ W,
    float* __restrict__ out, int N)
{
  const int lane   = threadIdx.x & 63;
  const int wid    = blockIdx.x * (blockDim.x >> 6) + (threadIdx.x >> 6);
  const int nwaves = gridDim.x * (blockDim.x >> 6);

  float Wr[8][8];
  #pragma unroll
  for (int k = 0; k < 8; ++k) {
    const float4 wa = *reinterpret_cast<const float4*>(W + (size_t)(lane*8 + k)*8);
    const float4 wb = *reinterpret_cast<const float4*>(W + (size_t)(lane*8 + k)*8 + 4);
    Wr[k][0]=wa.x; Wr[k][1]=wa.y; Wr[k][2]=wa.z; Wr[k][3]=wa.w;
    Wr[k][4]=wb.x; Wr[k][5]=wb.y; Wr[k][6]=wb.z; Wr[k][7]=wb.w;
  }

  for (int n = wid; n < N; n += nwaves) {
    const float* xr = x + (size_t)n * NFEAT + lane*8;
    const float4 a0 = *reinterpret_cast<const float4*>(xr);
    const float4 a1 = *reinterpret_cast<const float4*>(xr + 4);
    const float a[8] = {a0.x,a0.y,a0.z,a0.w,a1.x,a1.y,a1.z,a1.w};
    float acc[8] = {0.f,0.f,0.f,0.f,0.f,0.f,0.f,0.f};
    #pragma unroll
    for (int k = 0; k < 8; ++k)
      #pragma unroll
      for (int o = 0; o < 8; ++o)
        acc[o] = fmaf(a[k], Wr[k][o], acc[o]);
    #pragma unroll
    for (int o = 0; o < 8; ++o) {
      float v = acc[o];
      v += __shfl_xor(v, 32, 64); v += __shfl_xor(v, 16, 64);
      v += __shfl_xor(v,  8, 64); v += __shfl_xor(v,  4, 64);
      v += __shfl_xor(v,  2, 64); v += __shfl_xor(v,  1, 64);
      acc[o] = v;
    }
    if (lane == 0) {
      float4* op = reinterpret_cast<float4*>(out + (size_t)n*8);
      op[0] = make_float4(acc[0],acc[1],acc[2],acc[3]);
      op[1] = make_float4(acc[4],acc[5],acc[6],acc[7]);
    }
  }
}

// ============================================================================
// Phase B: CSR build. Histogram pass ALSO emits each edge's within-dst rank
// (the atomic's return value) so the placement is atomic-free.
// ============================================================================
__global__ __launch_bounds__(256) void gcn_hist_rank(
    const int* __restrict__ dst, int* __restrict__ deg,
    int* __restrict__ rank, int E)
{
  const int e = blockIdx.x * blockDim.x + threadIdx.x;
  if (e < E) rank[e] = atomicAdd(&deg[dst[e]], 1);   // coalesced rank store
}

__global__ __launch_bounds__(SCAN_BS) void gcn_scan_block(
    const int* __restrict__ deg, int* __restrict__ exc,
    int* __restrict__ bsums, int N)
{
  __shared__ int sm[SCAN_BS];
  const int i = blockIdx.x * SCAN_BS + threadIdx.x;
  const int v = (i < N) ? deg[i] : 0;
  sm[threadIdx.x] = v;
  __syncthreads();
  for (int off = 1; off < SCAN_BS; off <<= 1) {
    const int t = (threadIdx.x >= off) ? sm[threadIdx.x - off] : 0;
    __syncthreads();
    sm[threadIdx.x] += t;
    __syncthreads();
  }
  if (i < N) exc[i] = sm[threadIdx.x] - v;                 // exclusive-in-block
  if (threadIdx.x == SCAN_BS-1) bsums[blockIdx.x] = sm[threadIdx.x];
}

__global__ __launch_bounds__(1024) void gcn_scan_bsums(int* __restrict__ bsums, int NB)
{
  __shared__ int sm[1024];
  const int t = threadIdx.x;
  const int v = (t < NB) ? bsums[t] : 0;
  sm[t] = v;
  __syncthreads();
  for (int off = 1; off < 1024; off <<= 1) {
    const int u = (t >= off) ? sm[t - off] : 0;
    __syncthreads();
    sm[t] += u;
    __syncthreads();
  }
  if (t < NB) bsums[t] = sm[t] - v;                        // exclusive
}

__global__ __launch_bounds__(SCAN_BS) void gcn_scan_add(
    int* __restrict__ exc, const int* __restrict__ bsums, int N)
{
  const int i = blockIdx.x * SCAN_BS + threadIdx.x;
  if (i < N) exc[i] += bsums[blockIdx.x];
}

// bucket cursors start at each bucket's CSR base (free: rowoff[b*1024])
__global__ void gcn_bucket_init(const int* __restrict__ rowoff,
                                int* __restrict__ gcur, int NBUCK)
{
  const int b = blockIdx.x * blockDim.x + threadIdx.x;
  if (b < NBUCK) gcur[b] = rowoff[b << BUCK_SHIFT];
}

// ---- Pass 1: partition edges into dst-buckets (streaming-class writes). ----
// Per 2048-edge block: LDS histogram over <=128 buckets, ONE global atomic
// per touched bucket to claim a contiguous chunk, then ~252B bursts of
// (pos, payload) into the staging arrays. pos = rowoff[dst]+rank is exact.
__global__ __launch_bounds__(256) void gcn_partition(
    const int* __restrict__ src, const int* __restrict__ dst,
    const float* __restrict__ w, const int* __restrict__ rowoff,
    const int* __restrict__ rank, int* __restrict__ gcur,
    int* __restrict__ spos, int2* __restrict__ spay, int E)
{
  __shared__ int hist[128], base[128];
  const int tid = threadIdx.x;
  if (tid < 128) hist[tid] = 0;
  __syncthreads();

  const int e0 = blockIdx.x * (256 * PART_ITER);
  int d[PART_ITER], b[PART_ITER], lr[PART_ITER];
  #pragma unroll
  for (int j = 0; j < PART_ITER; ++j) {
    const int e = e0 + j*256 + tid;
    if (e < E) {
      d[j]  = dst[e];
      b[j]  = d[j] >> BUCK_SHIFT;
      lr[j] = atomicAdd(&hist[b[j]], 1);        // LDS atomic
    }
  }
  __syncthreads();
  if (tid < 128) {
    const int c = hist[tid];
    base[tid] = c ? atomicAdd(&gcur[tid], c) : 0;   // 1 global atomic/bucket
  }
  __syncthreads();
  #pragma unroll
  for (int j = 0; j < PART_ITER; ++j) {
    const int e = e0 + j*256 + tid;
    if (e < E) {
      const int slot = base[b[j]] + lr[j];
      spos[slot] = rowoff[d[j]] + rank[e];      // final CSR position
      spay[slot] = make_int2(src[e], __float_as_int(w[e]));
    }
  }
}

// ---- Pass 2: place payloads. slot and pos share a ~256KB bucket window, ----
// so the scattered 8B stores stay L2-resident and write back as full lines.
// Bijective XCD swizzle keeps consecutive-slot blocks on one XCD so cache
// lines aren't split across non-coherent L2s.
__global__ __launch_bounds__(256) void gcn_place(
    const int* __restrict__ spos, const int2* __restrict__ spay,
    int2* __restrict__ csr, int E, int nwg)
{
  const int q = nwg >> 3, r = nwg & 7;
  const int xcd = blockIdx.x & 7, i = blockIdx.x >> 3;
  const int lb = (xcd < r) ? (xcd*(q+1) + i) : (r*(q+1) + (xcd - r)*q + i);
  const int e0 = lb * (256 * PART_ITER);
  #pragma unroll
  for (int j = 0; j < PART_ITER; ++j) {
    const int s = e0 + j*256 + threadIdx.x;
    if (s < E) csr[spos[s]] = spay[s];
  }
}

// ---- Fallback single-pass scatter (v4, proven) if ws is too small ----
__global__ __launch_bounds__(256) void gcn_csr_scatter(
    const int* __restrict__ src, const int* __restrict__ dst,
    const float* __restrict__ w, const int* __restrict__ rowoff,
    const int* __restrict__ rank, int2* __restrict__ csr, int E)
{
  const int e = blockIdx.x * blockDim.x + threadIdx.x;
  if (e >= E) return;
  const int pos = rowoff[dst[e]] + rank[e];
  const unsigned long long payload =
      (unsigned long long)(unsigned)src[e] |
      ((unsigned long long)(unsigned)__float_as_int(w[e]) << 32);
  __builtin_nontemporal_store(payload, (unsigned long long*)&csr[pos]);
}

// ============================================================================
// Phase C: fused layer — 16 lanes per node (avg degree 32 -> ~2 edges/lane).
// ============================================================================
template<int FIN, int FOUT>
__global__ __launch_bounds__(256) void gcn_agg_layer(
    const int* __restrict__ rowoff, const int2* __restrict__ csr,
    const float* __restrict__ hin,
    const float* __restrict__ bias, const float* __restrict__ W,
    float* __restrict__ hout, int N, int E)
{
  const int sub = threadIdx.x & 15;
  const int n   = (blockIdx.x * blockDim.x + threadIdx.x) >> 4;
  if (n >= N) return;
  const int beg = rowoff[n];
  const int end = (n + 1 < N) ? rowoff[n + 1] : E;

  float acc[FIN];
  #pragma unroll
  for (int k = 0; k < FIN; ++k) acc[k] = 0.f;

  for (int e = beg + sub; e < end; e += 16) {
    const int2  sw = csr[e];
    const float wt = __int_as_float(sw.y);
    const float* hp = hin + (size_t)sw.x * FIN;
    if constexpr ((FIN & 3) == 0) {
      #pragma unroll
      for (int q = 0; q < FIN/4; ++q) {
        const float4 v = reinterpret_cast<const float4*>(hp)[q];
        acc[q*4+0] = fmaf(v.x, wt, acc[q*4+0]);
        acc[q*4+1] = fmaf(v.y, wt, acc[q*4+1]);
        acc[q*4+2] = fmaf(v.z, wt, acc[q*4+2]);
        acc[q*4+3] = fmaf(v.w, wt, acc[q*4+3]);
      }
    } else {
      #pragma unroll
      for (int q = 0; q < FIN/2; ++q) {
        const float2 v = reinterpret_cast<const float2*>(hp)[q];
        acc[q*2+0] = fmaf(v.x, wt, acc[q*2+0]);
        acc[q*2+1] = fmaf(v.y, wt, acc[q*2+1]);
      }
    }
  }
  #pragma unroll
  for (int k = 0; k < FIN; ++k) {
    float v = acc[k];
    v += __shfl_xor(v, 8, 64); v += __shfl_xor(v, 4, 64);
    v += __shfl_xor(v, 2, 64); v += __shfl_xor(v, 1, 64);
    acc[k] = v;                                  // every lane has the sum
  }
  #pragma unroll
  for (int k = 0; k < FIN; ++k) {
    const float t = acc[k] + bias[k];
    acc[k] = t > 0.f ? t : 0.f;
  }
  if (sub < FOUT) {
    float o = 0.f;
    #pragma unroll
    for (int k = 0; k < FIN; ++k)
      o = fmaf(acc[k], W[k*FOUT + sub], o);
    hout[(size_t)n*FOUT + sub] = o;
  }
}

__global__ __launch_bounds__(256) void gcn_agg_final(
    const int* __restrict__ rowoff, const int2* __restrict__ csr,
    const float* __restrict__ hin,
    const float* __restrict__ bias, float* __restrict__ out, int N, int E)
{
  const int sub = threadIdx.x & 15;
  const int n   = (blockIdx.x * blockDim.x + threadIdx.x) >> 4;
  if (n >= N) return;
  const int beg = rowoff[n];
  const int end = (n + 1 < N) ? rowoff[n + 1] : E;

  float acc[10];
  #pragma unroll
  for (int k = 0; k < 10; ++k) acc[k] = 0.f;

  for (int e = beg + sub; e < end; e += 16) {
    const int2  sw = csr[e];
    const float wt = __int_as_float(sw.y);
    const float* hp = hin + (size_t)sw.x * 10;
    #pragma unroll
    for (int q = 0; q < 5; ++q) {
      const float2 v = reinterpret_cast<const float2*>(hp)[q];
      acc[q*2+0] = fmaf(v.x, wt, acc[q*2+0]);
      acc[q*2+1] = fmaf(v.y, wt, acc[q*2+1]);
    }
  }
  #pragma unroll
  for (int k = 0; k < 10; ++k) {
    float v = acc[k];
    v += __shfl_xor(v, 8, 64); v += __shfl_xor(v, 4, 64);
    v += __shfl_xor(v, 2, 64); v += __shfl_xor(v, 1, 64);
    acc[k] = v + bias[k];
  }
  float m = acc[0];
  #pragma unroll
  for (int k = 1; k < 10; ++k) m = fmaxf(m, acc[k]);
  float s = 0.f;
  #pragma unroll
  for (int k = 0; k < 10; ++k) s += expf(acc[k] - m);
  const float ls = logf(s) + m;
  if (sub < 10)
    out[(size_t)n*10 + sub] = acc[sub] - ls;
}

// ============================================================================
extern "C" void kernel_launch(void* const* d_in, const int* in_sizes, int n_in,
                              void* d_out, int out_size, void* d_ws, size_t ws_size,
                              hipStream_t stream)
{
  const float* x  = (const float*)d_in[0];
  const int*   ei = (const int*)  d_in[1];
  const float* ew = (const float*)d_in[2];
  const float* W1 = (const float*)d_in[3];
  const float* b1 = (const float*)d_in[4];
  const float* W2 = (const float*)d_in[5];
  const float* b2 = (const float*)d_in[6];
  const float* W3 = (const float*)d_in[7];
  const float* b3 = (const float*)d_in[8];
  const float* W4 = (const float*)d_in[9];
  const float* b4 = (const float*)d_in[10];

  const int N = in_sizes[0] / NFEAT;     // 100000
  const int E = in_sizes[2];             // 3200000
  const int* src = ei;                   // edge_index[0]
  const int* dst = ei + E;               // edge_index[1]

  const int NB    = (N + SCAN_BS - 1) / SCAN_BS;      // blocks for node scans
  const int NBUCK = (N + (1 << BUCK_SHIFT) - 1) >> BUCK_SHIFT;   // 98

  const int eb   = (E + 255) / 256;
  const int nb16 = (N*16 + 255) / 256;
  const int pb   = (E + 256*PART_ITER - 1) / (256*PART_ITER);    // 1563

  // two-pass layout (ints): deg N | rowoff N | bsums 1024 | gcur 256 |
  //                         rank E | spos E | spay 2E | csr 2E
  const size_t need2 = ((size_t)2*N + 1024 + 256 + 6*(size_t)E) * 4;
  const bool twopass = (ws_size >= need2) && (NBUCK <= 128);

  int* wsp = (int*)d_ws;
  if (twopass) {
    int*   deg    = wsp;
    int*   rowoff = wsp + N;
    int*   bsums  = wsp + 2*(size_t)N;
    int*   gcur   = bsums + 1024;
    int*   rank   = gcur + 256;
    int*   spos   = rank + E;
    int2*  spay   = (int2*)(spos + E);
    int2*  csr    = spay + E;
    float* h8     = (float*)spos;      // aliases (dead after gcn_place)
    float* h16    = (float*)spay;      // aliases (dead after gcn_place)
    float* h10    = h16;               // h2p dead when h4p written
    float* outp   = (float*)d_out;

    hipMemsetAsync(deg, 0, (size_t)N*sizeof(int), stream);
    gcn_hist_rank<<<eb, 256, 0, stream>>>(dst, deg, rank, E);
    gcn_scan_block<<<NB, SCAN_BS, 0, stream>>>(deg, rowoff, bsums, N);
    gcn_scan_bsums<<<1, 1024, 0, stream>>>(bsums, NB);
    gcn_scan_add<<<NB, SCAN_BS, 0, stream>>>(rowoff, bsums, N);
    gcn_bucket_init<<<1, 128, 0, stream>>>(rowoff, gcur, NBUCK);
    gcn_partition<<<pb, 256, 0, stream>>>(src, dst, ew, rowoff, rank, gcur,
                                          spos, spay, E);
    gcn_place<<<pb, 256, 0, stream>>>(spos, spay, csr, E, pb);

    gcn_mm512x8<<<2048, 256, 0, stream>>>(x, W1, h8, N);
    gcn_agg_layer<8,16><<<nb16, 256, 0, stream>>>(rowoff, csr, h8,  b1, W2, h16, N, E);
    gcn_agg_layer<16,8><<<nb16, 256, 0, stream>>>(rowoff, csr, h16, b2, W3, h8,  N, E);
    gcn_agg_layer<8,10><<<nb16, 256, 0, stream>>>(rowoff, csr, h8,  b3, W4, h10, N, E);
    gcn_agg_final<<<nb16, 256, 0, stream>>>(rowoff, csr, h10, b4, outp, N, E);
  } else {
    // v4 fallback (proven): single-pass nt scatter
    int*   deg    = wsp;
    int*   rowoff = wsp + N;
    int*   bsums  = wsp + 2*(size_t)N;
    int*   rank   = wsp + 2*(size_t)N + 1024;
    int2*  csr    = (int2*)(rank + E);
    float* h8     = (float*)(csr + E);
    float* h16    = h8 + (size_t)N*8;
    float* h10    = h16;
    float* outp   = (float*)d_out;

    hipMemsetAsync(deg, 0, (size_t)N*sizeof(int), stream);
    gcn_hist_rank<<<eb, 256, 0, stream>>>(dst, deg, rank, E);
    gcn_scan_block<<<NB, SCAN_BS, 0, stream>>>(deg, rowoff, bsums, N);
    gcn_scan_bsums<<<1, 1024, 0, stream>>>(bsums, NB);
    gcn_scan_add<<<NB, SCAN_BS, 0, stream>>>(rowoff, bsums, N);
    gcn_csr_scatter<<<eb, 256, 0, stream>>>(src, dst, ew, rowoff, rank, csr, E);

    gcn_mm512x8<<<2048, 256, 0, stream>>>(x, W1, h8, N);
    gcn_agg_layer<8,16><<<nb16, 256, 0, stream>>>(rowoff, csr, h8,  b1, W2, h16, N, E);
    gcn_agg_layer<16,8><<<nb16, 256, 0, stream>>>(rowoff, csr, h16, b2, W3, h8,  N, E);
    gcn_agg_layer<8,10><<<nb16, 256, 0, stream>>>(rowoff, csr, h8,  b3, W4, h10, N, E);
    gcn_agg_final<<<nb16, 256, 0, stream>>>(rowoff, csr, h10, b4, outp, N, E);
  }
}

// Round 8
// 573.052 us; speedup vs baseline: 1.2565x; 1.2565x over previous
//
#include <hip/hip_runtime.h>
#include <hip/hip_bf16.h>
#include <math.h>

#define NFEAT 512
#define SCAN_BS 256
#define PART_ITER 16          // edges per thread in count/partition (4096/block)
#define BUCK_SHIFT 9          // 512 nodes per bucket -> ~128KB CSR window
#define SRC_BITS 17           // src < 2^17 (N=100000): key = dl<<17 | src
#define SRC_MASK ((1 << SRC_BITS) - 1)

// ============================================================================
// Phase A: h1p = x @ W1  ([N,512] @ [512,8]) — wave-per-node GEMV.
// Lane owns features [lane*8, lane*8+8); W1 fragment in 64 VGPRs preloaded
// once. Row read fully coalesced (64 lanes x 32B = 2KB). HBM floor: 205MB.
// ============================================================================
__global__ __launch_bounds__(256) void gcn_mm512x8(
    const float* __restrict__ x, const float* __restrict__ W,
    float* __restrict__ out, int N)
{
  const int lane   = threadIdx.x & 63;
  const int wid    = blockIdx.x * (blockDim.x >> 6) + (threadIdx.x >> 6);
  const int nwaves = gridDim.x * (blockDim.x >> 6);

  float Wr[8][8];
  #pragma unroll
  for (int k = 0; k < 8; ++k) {
    const float4 wa = *reinterpret_cast<const float4*>(W + (size_t)(lane*8 + k)*8);
    const float4 wb = *reinterpret_cast<const float4*>(W + (size_t)(lane*8 + k)*8 + 4);
    Wr[k][0]=wa.x; Wr[k][1]=wa.y; Wr[k][2]=wa.z; Wr[k][3]=wa.w;
    Wr[k][4]=wb.x; Wr[k][5]=wb.y; Wr[k][6]=wb.z; Wr[k][7]=wb.w;
  }

  for (int n = wid; n < N; n += nwaves) {
    const float* xr = x + (size_t)n * NFEAT + lane*8;
    const float4 a0 = *reinterpret_cast<const float4*>(xr);
    const float4 a1 = *reinterpret_cast<const float4*>(xr + 4);
    const float a[8] = {a0.x,a0.y,a0.z,a0.w,a1.x,a1.y,a1.z,a1.w};
    float acc[8] = {0.f,0.f,0.f,0.f,0.f,0.f,0.f,0.f};
    #pragma unroll
    for (int k = 0; k < 8; ++k)
      #pragma unroll
      for (int o = 0; o < 8; ++o)
        acc[o] = fmaf(a[k], Wr[k][o], acc[o]);
    #pragma unroll
    for (int o = 0; o < 8; ++o) {
      float v = acc[o];
      v += __shfl_xor(v, 32, 64); v += __shfl_xor(v, 16, 64);
      v += __shfl_xor(v,  8, 64); v += __shfl_xor(v,  4, 64);
      v += __shfl_xor(v,  2, 64); v += __shfl_xor(v,  1, 64);
      acc[o] = v;
    }
    if (lane == 0) {
      float4* op = reinterpret_cast<float4*>(out + (size_t)n*8);
      op[0] = make_float4(acc[0],acc[1],acc[2],acc[3]);
      op[1] = make_float4(acc[4],acc[5],acc[6],acc[7]);
    }
  }
}

// ============================================================================
// Phase B: binned CSR build — NO per-node global atomics anywhere.
// ============================================================================
// B0: per-bucket edge counts. LDS histogram; 1 global atomic/bucket/block.
__global__ __launch_bounds__(256) void gcn_bucket_count(
    const int* __restrict__ dst, int* __restrict__ bcnt, int E, int NBUCK)
{
  __shared__ int h[256];
  const int tid = threadIdx.x;
  h[tid] = 0;
  __syncthreads();
  const int e0 = blockIdx.x * (256 * PART_ITER);
  #pragma unroll
  for (int j = 0; j < PART_ITER; ++j) {
    const int e = e0 + j*256 + tid;
    if (e < E) atomicAdd(&h[dst[e] >> BUCK_SHIFT], 1);
  }
  __syncthreads();
  if (tid < NBUCK && h[tid]) atomicAdd(&bcnt[tid], h[tid]);
}

// B1: exclusive scan of <=255 bucket counts; writes bbase (+sentinel) & gcur
__global__ __launch_bounds__(256) void gcn_bucket_scan(
    const int* __restrict__ bcnt, int* __restrict__ bbase,
    int* __restrict__ gcur, int NBUCK, int E)
{
  __shared__ int sm[256];
  const int t = threadIdx.x;
  const int v = (t < NBUCK) ? bcnt[t] : 0;
  sm[t] = v;
  __syncthreads();
  for (int off = 1; off < 256; off <<= 1) {
    const int u = (t >= off) ? sm[t - off] : 0;
    __syncthreads();
    sm[t] += u;
    __syncthreads();
  }
  if (t < NBUCK) { bbase[t] = sm[t] - v; gcur[t] = sm[t] - v; }
  if (t == NBUCK) bbase[NBUCK] = E;          // sentinel (NBUCK < 256)
}

// B2: partition edges into bucket-contiguous staging. Per 4096-edge block:
// LDS histogram, one chunk-claim atomic per touched bucket, then burst
// writes of packed int2{dl<<17|src, w_bits}.
__global__ __launch_bounds__(256) void gcn_partition(
    const int* __restrict__ src, const int* __restrict__ dst,
    const float* __restrict__ w, int* __restrict__ gcur,
    int2* __restrict__ staged, int E, int NBUCK)
{
  __shared__ int hist[256], base[256];
  const int tid = threadIdx.x;
  hist[tid] = 0;
  __syncthreads();
  const int e0 = blockIdx.x * (256 * PART_ITER);
  int b_[PART_ITER], lr_[PART_ITER];
  #pragma unroll
  for (int j = 0; j < PART_ITER; ++j) {
    const int e = e0 + j*256 + tid;
    if (e < E) {
      b_[j]  = dst[e] >> BUCK_SHIFT;
      lr_[j] = atomicAdd(&hist[b_[j]], 1);        // LDS atomic
    }
  }
  __syncthreads();
  if (tid < NBUCK) {
    const int c = hist[tid];
    base[tid] = c ? atomicAdd(&gcur[tid], c) : 0; // 1 global atomic/bucket
  }
  __syncthreads();
  #pragma unroll
  for (int j = 0; j < PART_ITER; ++j) {
    const int e = e0 + j*256 + tid;
    if (e < E) {
      const int dl = dst[e] & ((1 << BUCK_SHIFT) - 1);   // L1-hot re-read
      staged[base[b_[j]] + lr_[j]] =
          make_int2((dl << SRC_BITS) | src[e], __float_as_int(w[e]));
    }
  }
}

// B3: per-bucket CSR finalize, one block per bucket, all counting in LDS.
// Histogram local nodes -> LDS scan -> rowoff (coalesced write) -> place
// edges into the bucket's own ~128KB CSR window (L2-resident writes).
__global__ __launch_bounds__(512) void gcn_build(
    const int2* __restrict__ staged, const int* __restrict__ bbase,
    int* __restrict__ rowoff, int2* __restrict__ csr, int N)
{
  __shared__ int h[512];
  __shared__ int cur[512];
  const int tid  = threadIdx.x;
  const int b    = blockIdx.x;
  const int base = bbase[b];
  const int cnt  = bbase[b + 1] - base;

  h[tid] = 0;
  __syncthreads();
  for (int s = tid; s < cnt; s += 512)
    atomicAdd(&h[staged[base + s].x >> SRC_BITS], 1);
  __syncthreads();
  const int v = h[tid];                           // inclusive Hillis-Steele
  for (int off = 1; off < 512; off <<= 1) {
    const int u = (tid >= off) ? h[tid - off] : 0;
    __syncthreads();
    h[tid] += u;
    __syncthreads();
  }
  const int excl = h[tid] - v;
  const int node = (b << BUCK_SHIFT) + tid;
  if (node < N) rowoff[node] = base + excl;
  cur[tid] = excl;
  __syncthreads();
  for (int s = tid; s < cnt; s += 512) {
    const int2 kv  = staged[base + s];
    const int  dl  = kv.x >> SRC_BITS;
    const int slot = atomicAdd(&cur[dl], 1);      // LDS atomic
    csr[base + slot] = make_int2(kv.x & SRC_MASK, kv.y);
  }
}

// ============================================================================
// Fallback CSR build (v4, proven) if ws/pack limits don't hold.
// ============================================================================
__global__ __launch_bounds__(256) void gcn_hist_rank(
    const int* __restrict__ dst, int* __restrict__ deg,
    int* __restrict__ rank, int E)
{
  const int e = blockIdx.x * blockDim.x + threadIdx.x;
  if (e < E) rank[e] = atomicAdd(&deg[dst[e]], 1);
}

__global__ __launch_bounds__(SCAN_BS) void gcn_scan_block(
    const int* __restrict__ deg, int* __restrict__ exc,
    int* __restrict__ bsums, int N)
{
  __shared__ int sm[SCAN_BS];
  const int i = blockIdx.x * SCAN_BS + threadIdx.x;
  const int v = (i < N) ? deg[i] : 0;
  sm[threadIdx.x] = v;
  __syncthreads();
  for (int off = 1; off < SCAN_BS; off <<= 1) {
    const int t = (threadIdx.x >= off) ? sm[threadIdx.x - off] : 0;
    __syncthreads();
    sm[threadIdx.x] += t;
    __syncthreads();
  }
  if (i < N) exc[i] = sm[threadIdx.x] - v;
  if (threadIdx.x == SCAN_BS-1) bsums[blockIdx.x] = sm[threadIdx.x];
}

__global__ __launch_bounds__(1024) void gcn_scan_bsums(int* __restrict__ bsums, int NB)
{
  __shared__ int sm[1024];
  const int t = threadIdx.x;
  const int v = (t < NB) ? bsums[t] : 0;
  sm[t] = v;
  __syncthreads();
  for (int off = 1; off < 1024; off <<= 1) {
    const int u = (t >= off) ? sm[t - off] : 0;
    __syncthreads();
    sm[t] += u;
    __syncthreads();
  }
  if (t < NB) bsums[t] = sm[t] - v;
}

__global__ __launch_bounds__(SCAN_BS) void gcn_scan_add(
    int* __restrict__ exc, const int* __restrict__ bsums, int N)
{
  const int i = blockIdx.x * SCAN_BS + threadIdx.x;
  if (i < N) exc[i] += bsums[blockIdx.x];
}

__global__ __launch_bounds__(256) void gcn_csr_scatter(
    const int* __restrict__ src, const int* __restrict__ dst,
    const float* __restrict__ w, const int* __restrict__ rowoff,
    const int* __restrict__ rank, int2* __restrict__ csr, int E)
{
  const int e = blockIdx.x * blockDim.x + threadIdx.x;
  if (e >= E) return;
  const int pos = rowoff[dst[e]] + rank[e];
  const unsigned long long payload =
      (unsigned long long)(unsigned)src[e] |
      ((unsigned long long)(unsigned)__float_as_int(w[e]) << 32);
  __builtin_nontemporal_store(payload, (unsigned long long*)&csr[pos]);
}

// ============================================================================
// Phase C: fused layer — 16 lanes per node (avg degree 32 -> ~2 edges/lane).
// ============================================================================
template<int FIN, int FOUT>
__global__ __launch_bounds__(256) void gcn_agg_layer(
    const int* __restrict__ rowoff, const int2* __restrict__ csr,
    const float* __restrict__ hin,
    const float* __restrict__ bias, const float* __restrict__ W,
    float* __restrict__ hout, int N, int E)
{
  const int sub = threadIdx.x & 15;
  const int n   = (blockIdx.x * blockDim.x + threadIdx.x) >> 4;
  if (n >= N) return;
  const int beg = rowoff[n];
  const int end = (n + 1 < N) ? rowoff[n + 1] : E;

  float acc[FIN];
  #pragma unroll
  for (int k = 0; k < FIN; ++k) acc[k] = 0.f;

  for (int e = beg + sub; e < end; e += 16) {
    const int2  sw = csr[e];
    const float wt = __int_as_float(sw.y);
    const float* hp = hin + (size_t)sw.x * FIN;
    if constexpr ((FIN & 3) == 0) {
      #pragma unroll
      for (int q = 0; q < FIN/4; ++q) {
        const float4 v = reinterpret_cast<const float4*>(hp)[q];
        acc[q*4+0] = fmaf(v.x, wt, acc[q*4+0]);
        acc[q*4+1] = fmaf(v.y, wt, acc[q*4+1]);
        acc[q*4+2] = fmaf(v.z, wt, acc[q*4+2]);
        acc[q*4+3] = fmaf(v.w, wt, acc[q*4+3]);
      }
    } else {
      #pragma unroll
      for (int q = 0; q < FIN/2; ++q) {
        const float2 v = reinterpret_cast<const float2*>(hp)[q];
        acc[q*2+0] = fmaf(v.x, wt, acc[q*2+0]);
        acc[q*2+1] = fmaf(v.y, wt, acc[q*2+1]);
      }
    }
  }
  #pragma unroll
  for (int k = 0; k < FIN; ++k) {
    float v = acc[k];
    v += __shfl_xor(v, 8, 64); v += __shfl_xor(v, 4, 64);
    v += __shfl_xor(v, 2, 64); v += __shfl_xor(v, 1, 64);
    acc[k] = v;                                  // every lane has the sum
  }
  #pragma unroll
  for (int k = 0; k < FIN; ++k) {
    const float t = acc[k] + bias[k];
    acc[k] = t > 0.f ? t : 0.f;
  }
  if (sub < FOUT) {
    float o = 0.f;
    #pragma unroll
    for (int k = 0; k < FIN; ++k)
      o = fmaf(acc[k], W[k*FOUT + sub], o);
    hout[(size_t)n*FOUT + sub] = o;
  }
}

__global__ __launch_bounds__(256) void gcn_agg_final(
    const int* __restrict__ rowoff, const int2* __restrict__ csr,
    const float* __restrict__ hin,
    const float* __restrict__ bias, float* __restrict__ out, int N, int E)
{
  const int sub = threadIdx.x & 15;
  const int n   = (blockIdx.x * blockDim.x + threadIdx.x) >> 4;
  if (n >= N) return;
  const int beg = rowoff[n];
  const int end = (n + 1 < N) ? rowoff[n + 1] : E;

  float acc[10];
  #pragma unroll
  for (int k = 0; k < 10; ++k) acc[k] = 0.f;

  for (int e = beg + sub; e < end; e += 16) {
    const int2  sw = csr[e];
    const float wt = __int_as_float(sw.y);
    const float* hp = hin + (size_t)sw.x * 10;
    #pragma unroll
    for (int q = 0; q < 5; ++q) {
      const float2 v = reinterpret_cast<const float2*>(hp)[q];
      acc[q*2+0] = fmaf(v.x, wt, acc[q*2+0]);
      acc[q*2+1] = fmaf(v.y, wt, acc[q*2+1]);
    }
  }
  #pragma unroll
  for (int k = 0; k < 10; ++k) {
    float v = acc[k];
    v += __shfl_xor(v, 8, 64); v += __shfl_xor(v, 4, 64);
    v += __shfl_xor(v, 2, 64); v += __shfl_xor(v, 1, 64);
    acc[k] = v + bias[k];
  }
  float m = acc[0];
  #pragma unroll
  for (int k = 1; k < 10; ++k) m = fmaxf(m, acc[k]);
  float s = 0.f;
  #pragma unroll
  for (int k = 0; k < 10; ++k) s += expf(acc[k] - m);
  const float ls = logf(s) + m;
  if (sub < 10)
    out[(size_t)n*10 + sub] = acc[sub] - ls;
}

// ============================================================================
extern "C" void kernel_launch(void* const* d_in, const int* in_sizes, int n_in,
                              void* d_out, int out_size, void* d_ws, size_t ws_size,
                              hipStream_t stream)
{
  const float* x  = (const float*)d_in[0];
  const int*   ei = (const int*)  d_in[1];
  const float* ew = (const float*)d_in[2];
  const float* W1 = (const float*)d_in[3];
  const float* b1 = (const float*)d_in[4];
  const float* W2 = (const float*)d_in[5];
  const float* b2 = (const float*)d_in[6];
  const float* W3 = (const float*)d_in[7];
  const float* b3 = (const float*)d_in[8];
  const float* W4 = (const float*)d_in[9];
  const float* b4 = (const float*)d_in[10];

  const int N = in_sizes[0] / NFEAT;     // 100000
  const int E = in_sizes[2];             // 3200000
  const int* src = ei;                   // edge_index[0]
  const int* dst = ei + E;               // edge_index[1]

  const int NBUCK = (N + (1 << BUCK_SHIFT) - 1) >> BUCK_SHIFT;   // 196
  const int eb    = (E + 255) / 256;
  const int nb16  = (N*16 + 255) / 256;
  const int pb    = (E + 256*PART_ITER - 1) / (256*PART_ITER);   // 782

  int* wsp = (int*)d_ws;

  // ---- binned layout (int offsets) ----
  //   [0,256)        bcnt
  //   [256,512)      bbase (NBUCK+1 = 197 used)
  //   [512,768)      gcur
  //   [768,768+N)    rowoff
  //   [S, S+2E)      staged (int2 E)   where S = 768+N (N even -> 8B aligned)
  //   [S+2E, S+4E)   csr    (int2 E)
  //   h8/h16/h10 alias staged (dead after gcn_build): 24N floats < 2E ints
  const size_t S     = 768 + (size_t)N;
  const size_t need2 = (S + 4*(size_t)E) * 4;
  const bool binned  = (ws_size >= need2) && (N <= (1 << SRC_BITS)) &&
                       (NBUCK < 256) && ((N & 1) == 0);

  if (binned) {
    int*   bcnt   = wsp;
    int*   bbase  = wsp + 256;
    int*   gcur   = wsp + 512;
    int*   rowoff = wsp + 768;
    int2*  staged = (int2*)(wsp + S);
    int2*  csr    = staged + E;
    float* h8     = (float*)staged;        // h1p, later h3p
    float* h16    = h8 + (size_t)N*8;      // h2p, later h4p region
    float* h10    = h16;                   // h4p aliases dead h2p
    float* outp   = (float*)d_out;

    hipMemsetAsync(bcnt, 0, 256*sizeof(int), stream);
    gcn_bucket_count<<<pb, 256, 0, stream>>>(dst, bcnt, E, NBUCK);
    gcn_bucket_scan<<<1, 256, 0, stream>>>(bcnt, bbase, gcur, NBUCK, E);
    gcn_partition<<<pb, 256, 0, stream>>>(src, dst, ew, gcur, staged, E, NBUCK);
    gcn_build<<<NBUCK, 512, 0, stream>>>(staged, bbase, rowoff, csr, N);

    gcn_mm512x8<<<2048, 256, 0, stream>>>(x, W1, h8, N);
    gcn_agg_layer<8,16><<<nb16, 256, 0, stream>>>(rowoff, csr, h8,  b1, W2, h16, N, E);
    gcn_agg_layer<16,8><<<nb16, 256, 0, stream>>>(rowoff, csr, h16, b2, W3, h8,  N, E);
    gcn_agg_layer<8,10><<<nb16, 256, 0, stream>>>(rowoff, csr, h8,  b3, W4, h10, N, E);
    gcn_agg_final<<<nb16, 256, 0, stream>>>(rowoff, csr, h10, b4, outp, N, E);
  } else {
    // ---- v4 fallback (proven) ----
    const int NB = (N + SCAN_BS - 1) / SCAN_BS;
    int*   deg    = wsp;
    int*   rowoff = wsp + N;
    int*   bsums  = wsp + 2*(size_t)N;
    int*   rank   = wsp + 2*(size_t)N + 1024;
    int2*  csr    = (int2*)(rank + E);
    float* h8     = (float*)(csr + E);
    float* h16    = h8 + (size_t)N*8;
    float* h10    = h16;
    float* outp   = (float*)d_out;

    hipMemsetAsync(deg, 0, (size_t)N*sizeof(int), stream);
    gcn_hist_rank<<<eb, 256, 0, stream>>>(dst, deg, rank, E);
    gcn_scan_block<<<NB, SCAN_BS, 0, stream>>>(deg, rowoff, bsums, N);
    gcn_scan_bsums<<<1, 1024, 0, stream>>>(bsums, NB);
    gcn_scan_add<<<NB, SCAN_BS, 0, stream>>>(rowoff, bsums, N);
    gcn_csr_scatter<<<eb, 256, 0, stream>>>(src, dst, ew, rowoff, rank, csr, E);

    gcn_mm512x8<<<2048, 256, 0, stream>>>(x, W1, h8, N);
    gcn_agg_layer<8,16><<<nb16, 256, 0, stream>>>(rowoff, csr, h8,  b1, W2, h16, N, E);
    gcn_agg_layer<16,8><<<nb16, 256, 0, stream>>>(rowoff, csr, h16, b2, W3, h8,  N, E);
    gcn_agg_layer<8,10><<<nb16, 256, 0, stream>>>(rowoff, csr, h8,  b3, W4, h10, N, E);
    gcn_agg_final<<<nb16, 256, 0, stream>>>(rowoff, csr, h10, b4, outp, N, E);
  }
}